// Round 5
// baseline (44.966 us; speedup 1.0000x reference)
//
#include <hip/hip_runtime.h>
#include <hip/hip_fp16.h>
#include <math.h>

#define BB 16
#define CC 3
#define HH 512
#define WW 512
#define HW (HH * WW)
#define KW 11
#define RAD 5

#define SEGV 8
#define NSEGV (HH / SEGV)          // 64 segments/image -> 1024 blocks
#define NITER (SEGV + KW - 1)      // 18 row iterations
#define LROW 524                   // padded row: col c at idx c+6; pads idx 1..5, 518..522

// ws layout: [0,4KB) ws_sq (1024 f), [4KB,8KB) ws_cos (1024 f). All slots
// are plainly stored every call -> no memset needed.

__global__ __launch_bounds__(256) void fused_band(
    const float* __restrict__ pred, const float* __restrict__ target,
    float* __restrict__ ws_sq, float* __restrict__ ws_cos)
{
    __shared__ float rb[2][3][LROW];
    __shared__ float red[8];

    const int tid = threadIdx.x;
    const int b   = blockIdx.x >> 6;            // / NSEGV
    const int seg = blockIdx.x & (NSEGV - 1);
    const int y0  = seg * SEGV;
    const long base = (long)b * (CC * HW);
    const int c0 = tid * 2;                     // owns columns c0, c0+1

    // one-time zero pads for horizontal boundary (both buffers, 3 maps)
    if (tid < 5) {
        #pragma unroll
        for (int pb = 0; pb < 2; ++pb)
            #pragma unroll
            for (int m = 0; m < 3; ++m) {
                rb[pb][m][1 + tid]   = 0.f;     // cols -5..-1
                rb[pb][m][518 + tid] = 0.f;     // cols 512..516
            }
    }

    // vertical ring (11 rows of horizontal sums), half2 packs the 2 columns
    __half2 ringd[11], ringp[11], ringt[11];
    float Sd0=0.f, Sd1=0.f, Sp0=0.f, Sp1=0.f, St0=0.f, St1=0.f;
    float sq = 0.f, cosacc = 0.f;

    // prefetch iteration 0 (T14: issue-early)
    float2 P0, P1, P2, T0, T1, T2;
    {
        const int y  = y0 - RAD;
        const int yc = y < 0 ? 0 : y;
        const long roff = base + (long)yc * WW + c0;
        P0 = *(const float2*)(pred + roff);
        P1 = *(const float2*)(pred + roff + HW);
        P2 = *(const float2*)(pred + roff + 2 * HW);
        T0 = *(const float2*)(target + roff);
        T1 = *(const float2*)(target + roff + HW);
        T2 = *(const float2*)(target + roff + 2 * HW);
    }

    #pragma unroll
    for (int it = 0; it < NITER; ++it) {
        const int y = y0 - RAD + it;
        const float msk = (y >= 0 && y < HH) ? 1.f : 0.f;

        const float2 p0 = P0, p1 = P1, p2 = P2, t0 = T0, t1 = T1, t2 = T2;
        if (it + 1 < NITER) {                   // prefetch next row
            const int y2  = y0 - RAD + it + 1;
            const int yc2 = min(max(y2, 0), HH - 1);
            const long roff2 = base + (long)yc2 * WW + c0;
            P0 = *(const float2*)(pred + roff2);
            P1 = *(const float2*)(pred + roff2 + HW);
            P2 = *(const float2*)(pred + roff2 + 2 * HW);
            T0 = *(const float2*)(target + roff2);
            T1 = *(const float2*)(target + roff2 + HW);
            T2 = *(const float2*)(target + roff2 + 2 * HW);
        }

        // per-pixel dot/pp/tt (masked for out-of-range rows)
        const float dx = (p0.x*t0.x + p1.x*t1.x + p2.x*t2.x) * msk;
        const float dy = (p0.y*t0.y + p1.y*t1.y + p2.y*t2.y) * msk;
        const float px = (p0.x*p0.x + p1.x*p1.x + p2.x*p2.x) * msk;
        const float py = (p0.y*p0.y + p1.y*p1.y + p2.y*p2.y) * msk;
        const float tx = (t0.x*t0.x + t1.x*t1.x + t2.x*t2.x) * msk;
        const float ty = (t0.y*t0.y + t1.y*t1.y + t2.y*t2.y) * msk;

        // PSNR squared error — only the 8 owned rows (counted once globally)
        if (it >= RAD && it < RAD + SEGV) {
            const float e0 = p0.x-t0.x, e1 = p1.x-t1.x, e2 = p2.x-t2.x;
            const float f0 = p0.y-t0.y, f1 = p1.y-t1.y, f2 = p2.y-t2.y;
            sq += e0*e0 + e1*e1 + e2*e2 + f0*f0 + f1*f1 + f2*f2;
        }

        const int pb = it & 1;
        *(float2*)&rb[pb][0][6 + c0] = make_float2(dx, dy);
        *(float2*)&rb[pb][1][6 + c0] = make_float2(px, py);
        *(float2*)&rb[pb][2][6 + c0] = make_float2(tx, ty);
        __syncthreads();

        // horizontal 11-sum for cols c0, c0+1 (sliding reuse)
        float hd0 = 0.f, hp0 = 0.f, ht0 = 0.f;
        #pragma unroll
        for (int k = 0; k < 11; ++k) {
            hd0 += rb[pb][0][c0 + 1 + k];
            hp0 += rb[pb][1][c0 + 1 + k];
            ht0 += rb[pb][2][c0 + 1 + k];
        }
        const float hd1 = hd0 - rb[pb][0][c0 + 1] + rb[pb][0][c0 + 12];
        const float hp1 = hp0 - rb[pb][1][c0 + 1] + rb[pb][1][c0 + 12];
        const float ht1 = ht0 - rb[pb][2][c0 + 1] + rb[pb][2][c0 + 12];

        // quantize to half2 FIRST, add the quantized value -> later subtract
        // of the identical value cancels exactly (no running-sum drift)
        const __half2 nd = __floats2half2_rn(hd0, hd1);
        const __half2 np = __floats2half2_rn(hp0, hp1);
        const __half2 nt = __floats2half2_rn(ht0, ht1);
        const float2 fd = __half22float2(nd);
        const float2 fp = __half22float2(np);
        const float2 ft = __half22float2(nt);
        Sd0 += fd.x; Sd1 += fd.y;
        Sp0 += fp.x; Sp1 += fp.y;
        St0 += ft.x; St1 += ft.y;

        if (it >= 10) {
            // S covers rows [y-10, y] = window of output row y-5
            cosacc += Sd0 / (sqrtf(Sp0 * St0) + 1e-6f);
            cosacc += Sd1 / (sqrtf(Sp1 * St1) + 1e-6f);
            const float2 od = __half22float2(ringd[(it + 1) % 11]);
            const float2 op = __half22float2(ringp[(it + 1) % 11]);
            const float2 ot = __half22float2(ringt[(it + 1) % 11]);
            Sd0 -= od.x; Sd1 -= od.y;
            Sp0 -= op.x; Sp1 -= op.y;
            St0 -= ot.x; St1 -= ot.y;
        }
        ringd[it % 11] = nd;
        ringp[it % 11] = np;
        ringt[it % 11] = nt;
    }

    // block reduce: two scalars
    #pragma unroll
    for (int o = 32; o > 0; o >>= 1) {
        cosacc += __shfl_down(cosacc, o);
        sq     += __shfl_down(sq, o);
    }
    const int wv = tid >> 6, ln = tid & 63;
    if (ln == 0) { red[wv] = cosacc; red[wv + 4] = sq; }
    __syncthreads();
    if (tid == 0) {
        ws_cos[blockIdx.x] = red[0] + red[1] + red[2] + red[3];
        ws_sq [blockIdx.x] = red[4] + red[5] + red[6] + red[7];
    }
}

// ---------------- finalize: 1024 sq partials + 1024 cos partials ----------------
__global__ __launch_bounds__(256) void finalize3(
    const float* __restrict__ ws_sq, const float* __restrict__ ws_cos,
    float* __restrict__ out)
{
    __shared__ float sq_b[16];
    __shared__ float cred[4];
    const int tid = threadIdx.x;

    // sq: 64 partials per image; 16 threads/image, 4 values each
    const int b = tid >> 4, j = tid & 15;
    float s = 0.f;
    #pragma unroll
    for (int k = 0; k < 4; ++k) s += ws_sq[b * 64 + j * 4 + k];
    #pragma unroll
    for (int o = 8; o > 0; o >>= 1) s += __shfl_down(s, o, 16);
    if (j == 0) sq_b[b] = s;

    float c = ws_cos[tid] + ws_cos[tid + 256] + ws_cos[tid + 512] + ws_cos[tid + 768];
    #pragma unroll
    for (int o = 32; o > 0; o >>= 1) c += __shfl_down(c, o);
    if ((tid & 63) == 0) cred[tid >> 6] = c;
    __syncthreads();

    if (tid == 0) {
        const float csum = cred[0] + cred[1] + cred[2] + cred[3];
        const float scale = 4.342944819032518f;   // 10 / ln(10)
        float lsum = 0.f;
        for (int bb = 0; bb < 16; ++bb)
            lsum += logf(sq_b[bb] / (float)(CC * HW) + 1e-8f);
        out[0] = scale * (lsum / (float)BB) + (1.f - csum / (float)(BB * HW));
    }
}

extern "C" void kernel_launch(void* const* d_in, const int* in_sizes, int n_in,
                              void* d_out, int out_size, void* d_ws, size_t ws_size,
                              hipStream_t stream)
{
    const float* pred   = (const float*)d_in[0];
    const float* target = (const float*)d_in[1];

    float* ws_sq  = (float*)d_ws;
    float* ws_cos = (float*)((char*)d_ws + 4096);

    fused_band<<<dim3(BB * NSEGV), 256, 0, stream>>>(pred, target, ws_sq, ws_cos);
    finalize3<<<1, 256, 0, stream>>>(ws_sq, ws_cos, (float*)d_out);
}

// Round 6
// 41.236 us; speedup vs baseline: 1.0904x; 1.0904x over previous
//
#include <hip/hip_runtime.h>
#include <hip/hip_fp16.h>
#include <math.h>

#define BB 16
#define CC 3
#define HH 512
#define WW 512
#define HW (HH * WW)
#define RAD 5
#define SEGV 8
#define NSEG (HH / SEGV)            // 64 segments per image
#define NSTRIP 5                    // 5 overlapping 128-col strips, 116 valid each
#define STRIPW 116
#define NTASK (BB * NSEG * NSTRIP)  // 5120 wave-tasks
#define NBLK (NTASK / 4)            // 1280 blocks (4 waves each)
#define NITER (SEGV + 2 * RAD)      // 18 row iterations

// Each wave owns a 128-col x SEGV-row strip: lane i holds cols (c0, c0+1).
// Horizontal 11-sum via in-wave shuffles on pair sums:
//   h(2i)   = b_{i-3} + sum_{j=i-2..i+2} p_j
//   h(2i+1) = sum_{j=i-2..i+2} p_j + a_{i+3}
// Valid output lanes: 3..60 (116 cols). No LDS, no barriers in the main loop.

__global__ __launch_bounds__(256) void fused_shfl(
    const float* __restrict__ pred, const float* __restrict__ target,
    float* __restrict__ ws_sq, float* __restrict__ ws_cos)
{
    __shared__ float red[8];
    const int tid  = threadIdx.x;
    const int wave = tid >> 6, lane = tid & 63;

    // bijective XCD-contiguous swizzle (1280 % 8 == 0): each XCD gets 160
    // consecutive blocks = 2 whole images -> vertical/strip halos stay in L2.
    const int bid = (int)blockIdx.x;
    const int swz = (bid & 7) * (NBLK / 8) + (bid >> 3);

    const int task  = swz * 4 + wave;
    const int img   = task / (NSEG * NSTRIP);
    const int rem   = task % (NSEG * NSTRIP);
    const int seg   = rem / NSTRIP;
    const int strip = rem - seg * NSTRIP;

    const int y0   = seg * SEGV;
    const int col0 = strip * STRIPW - 6 + lane * 2;      // even
    const int colc = min(max(col0, 0), WW - 2);
    const float mx = (col0 >= 0 && col0 < WW) ? 1.f : 0.f;
    const bool vout = (lane >= 3) && (lane <= 60) && (col0 < WW);

    const long base = (long)img * (CC * HW);

    // prefetch row 0 (issue-early)
    float2 P0, P1, P2, T0, T1, T2;
    {
        const int y  = y0 - RAD;
        const int yc = y < 0 ? 0 : y;
        const long off = base + (long)yc * WW + colc;
        P0 = *(const float2*)(pred + off);
        P1 = *(const float2*)(pred + off + HW);
        P2 = *(const float2*)(pred + off + 2 * HW);
        T0 = *(const float2*)(target + off);
        T1 = *(const float2*)(target + off + HW);
        T2 = *(const float2*)(target + off + 2 * HW);
    }

    __half2 ringd[11], ringp[11], ringt[11];
    float Sd0=0.f, Sd1=0.f, Sp0=0.f, Sp1=0.f, St0=0.f, St1=0.f;
    float sq = 0.f, cosacc = 0.f;

    #pragma unroll
    for (int it = 0; it < NITER; ++it) {
        const int y = y0 - RAD + it;
        const float msk = (y >= 0 && y < HH) ? mx : 0.f;

        const float2 p0=P0, p1=P1, p2=P2, t0=T0, t1=T1, t2=T2;
        if (it + 1 < NITER) {                     // prefetch next row
            const int y2  = y0 - RAD + it + 1;
            const int yc2 = min(max(y2, 0), HH - 1);
            const long off2 = base + (long)yc2 * WW + colc;
            P0 = *(const float2*)(pred + off2);
            P1 = *(const float2*)(pred + off2 + HW);
            P2 = *(const float2*)(pred + off2 + 2 * HW);
            T0 = *(const float2*)(target + off2);
            T1 = *(const float2*)(target + off2 + HW);
            T2 = *(const float2*)(target + off2 + 2 * HW);
        }

        // per-pixel dot/pp/tt, masked (zero padding outside image)
        const float ad = (p0.x*t0.x + p1.x*t1.x + p2.x*t2.x) * msk;
        const float bd = (p0.y*t0.y + p1.y*t1.y + p2.y*t2.y) * msk;
        const float ap = (p0.x*p0.x + p1.x*p1.x + p2.x*p2.x) * msk;
        const float bp = (p0.y*p0.y + p1.y*p1.y + p2.y*p2.y) * msk;
        const float at = (t0.x*t0.x + t1.x*t1.x + t2.x*t2.x) * msk;
        const float bt = (t0.y*t0.y + t1.y*t1.y + t2.y*t2.y) * msk;

        // PSNR squared error: owned rows x valid (non-overlapping) cols only
        if (it >= RAD && it < RAD + SEGV && vout) {
            const float e0=p0.x-t0.x, e1=p1.x-t1.x, e2=p2.x-t2.x;
            const float f0=p0.y-t0.y, f1=p1.y-t1.y, f2=p2.y-t2.y;
            sq += e0*e0 + e1*e1 + e2*e2 + f0*f0 + f1*f1 + f2*f2;
        }

        // horizontal 11-window via shuffles (6 per map)
        float h0d, h1d, h0p, h1p, h0t, h1t;
        {
            const float pr = ad + bd;
            const float u1 = pr + __shfl(pr, lane + 1);
            const float u2 = u1 + __shfl(u1, lane + 2);
            const float u3 = u2 + __shfl(pr, lane + 4);   // p_i..p_{i+4}
            const float S5 = __shfl(u3, lane - 2);        // p_{i-2}..p_{i+2}
            h0d = __shfl(bd, lane - 3) + S5;
            h1d = S5 + __shfl(ad, lane + 3);
        }
        {
            const float pr = ap + bp;
            const float u1 = pr + __shfl(pr, lane + 1);
            const float u2 = u1 + __shfl(u1, lane + 2);
            const float u3 = u2 + __shfl(pr, lane + 4);
            const float S5 = __shfl(u3, lane - 2);
            h0p = __shfl(bp, lane - 3) + S5;
            h1p = S5 + __shfl(ap, lane + 3);
        }
        {
            const float pr = at + bt;
            const float u1 = pr + __shfl(pr, lane + 1);
            const float u2 = u1 + __shfl(u1, lane + 2);
            const float u3 = u2 + __shfl(pr, lane + 4);
            const float S5 = __shfl(u3, lane - 2);
            h0t = __shfl(bt, lane - 3) + S5;
            h1t = S5 + __shfl(at, lane + 3);
        }

        // quantize FIRST, accumulate quantized -> ring subtract cancels exactly
        const __half2 nd = __floats2half2_rn(h0d, h1d);
        const __half2 np = __floats2half2_rn(h0p, h1p);
        const __half2 nt = __floats2half2_rn(h0t, h1t);
        const float2 fd = __half22float2(nd);
        const float2 fp = __half22float2(np);
        const float2 ft = __half22float2(nt);
        Sd0 += fd.x; Sd1 += fd.y;
        Sp0 += fp.x; Sp1 += fp.y;
        St0 += ft.x; St1 += ft.y;

        if (it >= 10) {
            if (vout) {   // select (not multiply) -> NaN-safe for masked lanes
                cosacc += Sd0 / (sqrtf(Sp0) * sqrtf(St0) + 1e-6f);
                cosacc += Sd1 / (sqrtf(Sp1) * sqrtf(St1) + 1e-6f);
            }
            const float2 od = __half22float2(ringd[(it + 1) % 11]);
            const float2 op = __half22float2(ringp[(it + 1) % 11]);
            const float2 ot = __half22float2(ringt[(it + 1) % 11]);
            Sd0 -= od.x; Sd1 -= od.y;
            Sp0 -= op.x; Sp1 -= op.y;
            St0 -= ot.x; St1 -= ot.y;
        }
        ringd[it % 11] = nd;
        ringp[it % 11] = np;
        ringt[it % 11] = nt;
    }

    // wave reduce -> block partials (one barrier total)
    #pragma unroll
    for (int o = 32; o > 0; o >>= 1) {
        cosacc += __shfl_down(cosacc, o);
        sq     += __shfl_down(sq, o);
    }
    if (lane == 0) { red[wave] = cosacc; red[wave + 4] = sq; }
    __syncthreads();
    if (tid == 0) {
        // store under swz so finalize's img mapping (80 blocks/img) holds
        ws_cos[swz] = red[0] + red[1] + red[2] + red[3];
        ws_sq [swz] = red[4] + red[5] + red[6] + red[7];
    }
}

// ---------------- finalize: 1280 sq + 1280 cos partials ----------------
__global__ __launch_bounds__(256) void finalize4(
    const float* __restrict__ ws_sq, const float* __restrict__ ws_cos,
    float* __restrict__ out)
{
    __shared__ float sq_b[16];
    __shared__ float cred[4];
    const int tid = threadIdx.x;

    // sq: 80 partials per image; 16 threads/image, 5 values each
    const int b = tid >> 4, j = tid & 15;
    float s = 0.f;
    #pragma unroll
    for (int k = 0; k < 5; ++k) s += ws_sq[b * 80 + j * 5 + k];
    #pragma unroll
    for (int o = 8; o > 0; o >>= 1) s += __shfl_down(s, o, 16);
    if (j == 0) sq_b[b] = s;

    float c = 0.f;
    #pragma unroll
    for (int k = 0; k < 5; ++k) c += ws_cos[tid + 256 * k];
    #pragma unroll
    for (int o = 32; o > 0; o >>= 1) c += __shfl_down(c, o);
    if ((tid & 63) == 0) cred[tid >> 6] = c;
    __syncthreads();

    if (tid == 0) {
        const float csum = cred[0] + cred[1] + cred[2] + cred[3];
        const float scale = 4.342944819032518f;   // 10 / ln(10)
        float lsum = 0.f;
        for (int bb = 0; bb < 16; ++bb)
            lsum += logf(sq_b[bb] / (float)(CC * HW) + 1e-8f);
        out[0] = scale * (lsum / (float)BB) + (1.f - csum / (float)(BB * HW));
    }
}

extern "C" void kernel_launch(void* const* d_in, const int* in_sizes, int n_in,
                              void* d_out, int out_size, void* d_ws, size_t ws_size,
                              hipStream_t stream)
{
    const float* pred   = (const float*)d_in[0];
    const float* target = (const float*)d_in[1];

    float* ws_sq  = (float*)d_ws;                        // 1280 floats
    float* ws_cos = (float*)((char*)d_ws + 8192);        // 1280 floats

    fused_shfl<<<dim3(NBLK), 256, 0, stream>>>(pred, target, ws_sq, ws_cos);
    finalize4<<<1, 256, 0, stream>>>(ws_sq, ws_cos, (float*)d_out);
}

// Round 7
// 34.871 us; speedup vs baseline: 1.2895x; 1.1825x over previous
//
#include <hip/hip_runtime.h>
#include <hip/hip_fp16.h>
#include <math.h>

#define BB 16
#define CC 3
#define HH 512
#define WW 512
#define HW (HH * WW)
#define RAD 5
#define SEGV 16
#define NSEG (HH / SEGV)            // 32 segments per image
#define NSTRIP 5                    // 5 overlapping 128-col strips, 116 valid each
#define STRIPW 116
#define NTASK (BB * NSEG * NSTRIP)  // 2560 wave-tasks
#define NBLK (NTASK / 2)            // 1280 blocks (2 waves each)
#define NITER (SEGV + 2 * RAD)      // 26 row iterations

__device__ __forceinline__ __half2 shfl_h2(__half2 v, int src) {
    union { __half2 h; int i; } u;
    u.h = v;
    u.i = __shfl(u.i, src);
    return u.h;
}

// Wave owns a 128-col strip (lane: cols c0,c0+1), SEGV valid rows.
// Horizontal 11-sum: {dot,pp} packed half2 tree (6 shuffles), tt f32 tree
// (6 shuffles). Vertical: 11-deep half2 register ring, exact-cancellation
// f32 running sums. No LDS/barriers in the main loop.
__global__ __launch_bounds__(128) void fused_shfl(
    const float* __restrict__ pred, const float* __restrict__ target,
    float* __restrict__ ws_sq, float* __restrict__ ws_cos)
{
    __shared__ float red[4];
    const int tid  = threadIdx.x;
    const int wave = tid >> 6, lane = tid & 63;

    // bijective XCD-contiguous swizzle (1280 % 8 == 0)
    const int bid = (int)blockIdx.x;
    const int swz = (bid & 7) * (NBLK / 8) + (bid >> 3);

    const int task  = swz * 2 + wave;
    const int img   = task / (NSEG * NSTRIP);
    const int rem   = task % (NSEG * NSTRIP);
    const int seg   = rem / NSTRIP;
    const int strip = rem - seg * NSTRIP;

    const int y0   = seg * SEGV;
    const int col0 = strip * STRIPW - 6 + lane * 2;      // even
    const int colc = min(max(col0, 0), WW - 2);
    const float mx = (col0 >= 0 && col0 < WW) ? 1.f : 0.f;
    const bool vout = (lane >= 3) && (lane <= 60) && (col0 < WW);

    const long base = (long)img * (CC * HW);

    // prefetch row 0 (issue-early)
    float2 P0, P1, P2, T0, T1, T2;
    {
        const int y  = y0 - RAD;
        const int yc = y < 0 ? 0 : y;
        const long off = base + (long)yc * WW + colc;
        P0 = *(const float2*)(pred + off);
        P1 = *(const float2*)(pred + off + HW);
        P2 = *(const float2*)(pred + off + 2 * HW);
        T0 = *(const float2*)(target + off);
        T1 = *(const float2*)(target + off + HW);
        T2 = *(const float2*)(target + off + 2 * HW);
    }

    __half2 ring0[11], ring1[11], ringT[11];   // (hd0,hp0), (hd1,hp1), (ht0,ht1)
    float Sd0=0.f, Sd1=0.f, Sp0=0.f, Sp1=0.f, St0=0.f, St1=0.f;
    float sq = 0.f, cosacc = 0.f;

    #pragma unroll
    for (int it = 0; it < NITER; ++it) {
        const int y = y0 - RAD + it;
        const float msk = (y >= 0 && y < HH) ? mx : 0.f;

        const float2 p0=P0, p1=P1, p2=P2, t0=T0, t1=T1, t2=T2;
        if (it + 1 < NITER) {                     // prefetch next row
            const int y2  = y0 - RAD + it + 1;
            const int yc2 = min(max(y2, 0), HH - 1);
            const long off2 = base + (long)yc2 * WW + colc;
            P0 = *(const float2*)(pred + off2);
            P1 = *(const float2*)(pred + off2 + HW);
            P2 = *(const float2*)(pred + off2 + 2 * HW);
            T0 = *(const float2*)(target + off2);
            T1 = *(const float2*)(target + off2 + HW);
            T2 = *(const float2*)(target + off2 + 2 * HW);
        }

        // per-pixel dot/pp/tt, masked (zero padding outside image)
        const float ad = (p0.x*t0.x + p1.x*t1.x + p2.x*t2.x) * msk;
        const float bd = (p0.y*t0.y + p1.y*t1.y + p2.y*t2.y) * msk;
        const float ap = (p0.x*p0.x + p1.x*p1.x + p2.x*p2.x) * msk;
        const float bp = (p0.y*p0.y + p1.y*p1.y + p2.y*p2.y) * msk;
        const float at = (t0.x*t0.x + t1.x*t1.x + t2.x*t2.x) * msk;
        const float bt = (t0.y*t0.y + t1.y*t1.y + t2.y*t2.y) * msk;

        // PSNR squared error: owned rows x valid cols only
        if (it >= RAD && it < RAD + SEGV && vout) {
            const float e0=p0.x-t0.x, e1=p1.x-t1.x, e2=p2.x-t2.x;
            const float f0=p0.y-t0.y, f1=p1.y-t1.y, f2=p2.y-t2.y;
            sq += e0*e0 + e1*e1 + e2*e2 + f0*f0 + f1*f1 + f2*f2;
        }

        // ---- horizontal 11-window ----
        // packed {d,p} half2 tree: h(2i)=b_{i-3}+S5, h(2i+1)=S5+a_{i+3}
        __half2 h0dp, h1dp;
        {
            const __half2 Pk = __floats2half2_rn(ad + bd, ap + bp);
            const __half2 Ak = __floats2half2_rn(ad, ap);
            const __half2 Bk = __floats2half2_rn(bd, bp);
            const __half2 u1 = __hadd2(Pk, shfl_h2(Pk, lane + 1));
            const __half2 u2 = __hadd2(u1, shfl_h2(u1, lane + 2));
            const __half2 u3 = __hadd2(u2, shfl_h2(Pk, lane + 4));
            const __half2 S5 = shfl_h2(u3, lane - 2);
            h0dp = __hadd2(shfl_h2(Bk, lane - 3), S5);
            h1dp = __hadd2(S5, shfl_h2(Ak, lane + 3));
        }
        // tt f32 tree
        __half2 hT;
        {
            const float pr = at + bt;
            const float u1 = pr + __shfl(pr, lane + 1);
            const float u2 = u1 + __shfl(u1, lane + 2);
            const float u3 = u2 + __shfl(pr, lane + 4);
            const float S5 = __shfl(u3, lane - 2);
            hT = __floats2half2_rn(__shfl(bt, lane - 3) + S5,
                                   S5 + __shfl(at, lane + 3));
        }

        // accumulate the QUANTIZED values -> ring subtract cancels exactly
        const float2 f0 = __half22float2(h0dp);   // (hd0, hp0)
        const float2 f1 = __half22float2(h1dp);   // (hd1, hp1)
        const float2 fT = __half22float2(hT);     // (ht0, ht1)
        Sd0 += f0.x; Sp0 += f0.y;
        Sd1 += f1.x; Sp1 += f1.y;
        St0 += fT.x; St1 += fT.y;

        if (it >= 10) {
            if (vout) {
                cosacc += Sd0 / (sqrtf(fmaxf(Sp0 * St0, 0.f)) + 1e-6f);
                cosacc += Sd1 / (sqrtf(fmaxf(Sp1 * St1, 0.f)) + 1e-6f);
            }
            const float2 o0 = __half22float2(ring0[(it + 1) % 11]);
            const float2 o1 = __half22float2(ring1[(it + 1) % 11]);
            const float2 oT = __half22float2(ringT[(it + 1) % 11]);
            Sd0 -= o0.x; Sp0 -= o0.y;
            Sd1 -= o1.x; Sp1 -= o1.y;
            St0 -= oT.x; St1 -= oT.y;
        }
        ring0[it % 11] = h0dp;
        ring1[it % 11] = h1dp;
        ringT[it % 11] = hT;
    }

    // wave reduce -> block partials
    #pragma unroll
    for (int o = 32; o > 0; o >>= 1) {
        cosacc += __shfl_down(cosacc, o);
        sq     += __shfl_down(sq, o);
    }
    if (lane == 0) { red[wave] = cosacc; red[wave + 2] = sq; }
    __syncthreads();
    if (tid == 0) {
        ws_cos[swz] = red[0] + red[1];
        ws_sq [swz] = red[2] + red[3];
    }
}

// ---------------- finalize: 1280 sq + 1280 cos partials ----------------
__global__ __launch_bounds__(256) void finalize4(
    const float* __restrict__ ws_sq, const float* __restrict__ ws_cos,
    float* __restrict__ out)
{
    __shared__ float sq_b[16];
    __shared__ float cred[4];
    const int tid = threadIdx.x;

    // sq: 80 partials per image; 16 threads/image, 5 values each
    const int b = tid >> 4, j = tid & 15;
    float s = 0.f;
    #pragma unroll
    for (int k = 0; k < 5; ++k) s += ws_sq[b * 80 + j * 5 + k];
    #pragma unroll
    for (int o = 8; o > 0; o >>= 1) s += __shfl_down(s, o, 16);
    if (j == 0) sq_b[b] = s;

    float c = 0.f;
    #pragma unroll
    for (int k = 0; k < 5; ++k) c += ws_cos[tid + 256 * k];
    #pragma unroll
    for (int o = 32; o > 0; o >>= 1) c += __shfl_down(c, o);
    if ((tid & 63) == 0) cred[tid >> 6] = c;
    __syncthreads();

    if (tid == 0) {
        const float csum = cred[0] + cred[1] + cred[2] + cred[3];
        const float scale = 4.342944819032518f;   // 10 / ln(10)
        float lsum = 0.f;
        for (int bb = 0; bb < 16; ++bb)
            lsum += logf(sq_b[bb] / (float)(CC * HW) + 1e-8f);
        out[0] = scale * (lsum / (float)BB) + (1.f - csum / (float)(BB * HW));
    }
}

extern "C" void kernel_launch(void* const* d_in, const int* in_sizes, int n_in,
                              void* d_out, int out_size, void* d_ws, size_t ws_size,
                              hipStream_t stream)
{
    const float* pred   = (const float*)d_in[0];
    const float* target = (const float*)d_in[1];

    float* ws_sq  = (float*)d_ws;                        // 1280 floats
    float* ws_cos = (float*)((char*)d_ws + 8192);        // 1280 floats

    fused_shfl<<<dim3(NBLK), 128, 0, stream>>>(pred, target, ws_sq, ws_cos);
    finalize4<<<1, 256, 0, stream>>>(ws_sq, ws_cos, (float*)d_out);
}